// Round 2
// baseline (2807.510 us; speedup 1.0000x reference)
//
#include <hip/hip_runtime.h>
#include <hip/hip_bf16.h>
#include <math.h>

#define IN_C 256
#define NEG 0.2f

// order-preserving float atomic max; works with memory initialized to 0xFFFFFFFF.
// Branch on the SIGN BIT (not float >=) so -0.0f takes the unsigned-min path.
__device__ __forceinline__ void atomicMaxF(float* addr, float v) {
    if (__float_as_int(v) >= 0) atomicMax((int*)addr, __float_as_int(v));
    else                        atomicMin((unsigned int*)addr, __float_as_uint(v));
}

// Y[N][COLS] = X[N][256] @ W[256][COLS]; block = COLS*RG threads, 32 rows/block
template<int COLS, int RG>
__global__ __launch_bounds__(COLS*RG) void gemm_k256(
        const float* __restrict__ X, const float* __restrict__ W,
        float* __restrict__ Y, int nrows) {
    constexpr int ROWS = 32;
    constexpr int RPT  = ROWS / RG;
    __shared__ float xs[ROWS][IN_C];
    const int tid   = threadIdx.x;
    const int rbase = blockIdx.x * ROWS;

    const int TOT4 = ROWS * IN_C / 4;
    const float4* X4 = (const float4*)(X + (size_t)rbase * IN_C);
    const int valid_rows = min(nrows - rbase, ROWS);
    const int maxi4 = valid_rows * (IN_C / 4);
    for (int i = tid; i < TOT4; i += COLS * RG) {
        float4 v = (i < maxi4) ? X4[i] : make_float4(0.f, 0.f, 0.f, 0.f);
        ((float4*)xs)[i] = v;
    }
    __syncthreads();

    const int col = tid % COLS;
    const int rg  = tid / COLS;
    float acc[RPT];
#pragma unroll
    for (int r = 0; r < RPT; ++r) acc[r] = 0.f;

    for (int k = 0; k < IN_C; k += 4) {
        float w0 = W[(size_t)(k + 0) * COLS + col];
        float w1 = W[(size_t)(k + 1) * COLS + col];
        float w2 = W[(size_t)(k + 2) * COLS + col];
        float w3 = W[(size_t)(k + 3) * COLS + col];
#pragma unroll
        for (int r = 0; r < RPT; ++r) {
            float4 xv = *(const float4*)&xs[rg * RPT + r][k];
            acc[r] = fmaf(xv.x, w0, acc[r]);
            acc[r] = fmaf(xv.y, w1, acc[r]);
            acc[r] = fmaf(xv.z, w2, acc[r]);
            acc[r] = fmaf(xv.w, w3, acc[r]);
        }
    }
#pragma unroll
    for (int r = 0; r < RPT; ++r) {
        int row = rbase + rg * RPT + r;
        if (row < nrows) Y[(size_t)row * COLS + col] = acc[r];
    }
}

// per-node attention dots, 2 heads, row width 256 (wave per node)
__global__ void attdots_h2(const float* __restrict__ H, const float* __restrict__ asrc,
                           const float* __restrict__ adst, float* __restrict__ a_s,
                           float* __restrict__ a_d, int n_nodes) {
    int node = blockIdx.x * (blockDim.x >> 6) + (threadIdx.x >> 6);
    if (node >= n_nodes) return;
    int lane = threadIdx.x & 63;
    float4 hv = ((const float4*)(H + (size_t)node * 256))[lane];
    float4 sv = ((const float4*)asrc)[lane];
    float4 dv = ((const float4*)adst)[lane];
    float ps = hv.x * sv.x + hv.y * sv.y + hv.z * sv.z + hv.w * sv.w;
    float pd = hv.x * dv.x + hv.y * dv.y + hv.z * dv.z + hv.w * dv.w;
#pragma unroll
    for (int off = 16; off; off >>= 1) {
        ps += __shfl_down(ps, off, 32);
        pd += __shfl_down(pd, off, 32);
    }
    if ((lane & 31) == 0) {
        int h = lane >> 5;
        a_s[node * 2 + h] = ps;
        a_d[node * 2 + h] = pd;
    }
}

// per-node attention dots, 1 head, row width 128 (wave per node)
__global__ void attdots_h1(const float* __restrict__ H, const float* __restrict__ asrc,
                           const float* __restrict__ adst, float* __restrict__ a_s,
                           float* __restrict__ a_d, int n_nodes) {
    int node = blockIdx.x * (blockDim.x >> 6) + (threadIdx.x >> 6);
    if (node >= n_nodes) return;
    int lane = threadIdx.x & 63;
    float2 hv = ((const float2*)(H + (size_t)node * 128))[lane];
    float2 sv = ((const float2*)asrc)[lane];
    float2 dv = ((const float2*)adst)[lane];
    float ps = hv.x * sv.x + hv.y * sv.y;
    float pd = hv.x * dv.x + hv.y * dv.y;
#pragma unroll
    for (int off = 32; off; off >>= 1) {
        ps += __shfl_down(ps, off, 64);
        pd += __shfl_down(pd, off, 64);
    }
    if (lane == 0) { a_s[node] = ps; a_d[node] = pd; }
}

// edge alpha + segment max, 2 heads
__global__ void edge_alpha2h(const int* __restrict__ ei, int E_, int etot,
                             const float* __restrict__ a_s, const float* __restrict__ a_d,
                             float* __restrict__ alpha, float* __restrict__ m) {
    int e = blockIdx.x * blockDim.x + threadIdx.x;
    if (e >= etot) return;
    int src, dst;
    if (e < E_) { src = ei[e]; dst = ei[E_ + e]; } else { src = dst = e - E_; }
#pragma unroll
    for (int h = 0; h < 2; ++h) {
        float v = a_s[src * 2 + h] + a_d[dst * 2 + h];
        v = (v > 0.f) ? v : NEG * v;
        alpha[(size_t)e * 2 + h] = v;
        atomicMaxF(&m[dst * 2 + h], v);
    }
}

// edge alpha + segment max, 1 head
__global__ void edge_alpha1h(const int* __restrict__ ei, int E_, int etot,
                             const float* __restrict__ a_s, const float* __restrict__ a_d,
                             float* __restrict__ alpha, float* __restrict__ m) {
    int e = blockIdx.x * blockDim.x + threadIdx.x;
    if (e >= etot) return;
    int src, dst;
    if (e < E_) { src = ei[e]; dst = ei[E_ + e]; } else { src = dst = e - E_; }
    float v = a_s[src] + a_d[dst];
    v = (v > 0.f) ? v : NEG * v;
    alpha[e] = v;
    atomicMaxF(&m[dst], v);
}

// edge aggregation layer1: acc[dst] += h1[src]*exp(alpha-m), den[dst] += exp
// one wave per edge, 256 floats/row (2 heads x 128)
__global__ void edge_aggr_l1(const int* __restrict__ ei, int E_, int etot,
                             const float* __restrict__ H, const float* __restrict__ alpha,
                             const float* __restrict__ m, float* __restrict__ denom,
                             float* __restrict__ acc) {
    int e = blockIdx.x * (blockDim.x >> 6) + (threadIdx.x >> 6);
    if (e >= etot) return;
    int lane = threadIdx.x & 63;
    int src, dst;
    if (e < E_) { src = ei[e]; dst = ei[E_ + e]; } else { src = dst = e - E_; }
    int h = lane >> 5;
    float ev = __expf(alpha[(size_t)e * 2 + h] - m[dst * 2 + h]);
    if ((lane & 31) == 0) atomicAdd(&denom[dst * 2 + h], ev);
    float4 v = ((const float4*)(H + (size_t)src * 256))[lane];
    float* o = acc + (size_t)dst * 256 + lane * 4;
    atomicAdd(o + 0, v.x * ev);
    atomicAdd(o + 1, v.y * ev);
    atomicAdd(o + 2, v.z * ev);
    atomicAdd(o + 3, v.w * ev);
}

// edge aggregation layer2: 1 head x 128
__global__ void edge_aggr_l2(const int* __restrict__ ei, int E_, int etot,
                             const float* __restrict__ H, const float* __restrict__ alpha,
                             const float* __restrict__ m, float* __restrict__ denom,
                             float* __restrict__ acc) {
    int e = blockIdx.x * (blockDim.x >> 6) + (threadIdx.x >> 6);
    if (e >= etot) return;
    int lane = threadIdx.x & 63;
    int src, dst;
    if (e < E_) { src = ei[e]; dst = ei[E_ + e]; } else { src = dst = e - E_; }
    float ev = __expf(alpha[e] - m[dst]);
    if (lane == 0) atomicAdd(&denom[dst], ev);
    float2 v = ((const float2*)(H + (size_t)src * 128))[lane];
    float* o = acc + (size_t)dst * 128 + lane * 2;
    atomicAdd(o + 0, v.x * ev);
    atomicAdd(o + 1, v.y * ev);
}

// finalize layer1: acc = elu(acc/den + b1)   (float4 over N*256)
__global__ void finalize1(float* __restrict__ acc, const float* __restrict__ denom,
                          const float* __restrict__ bias, int n_nodes) {
    int idx = blockIdx.x * blockDim.x + threadIdx.x;
    int tot = n_nodes * 64;            // float4s per row = 64
    if (idx >= tot) return;
    int n  = idx >> 6;
    int c4 = idx & 63;
    int h  = c4 >> 5;
    float inv = 1.f / (denom[n * 2 + h] + 1e-16f);
    float4 v = ((float4*)acc)[idx];
    float4 b = ((const float4*)bias)[c4];
    float t;
    t = v.x * inv + b.x; v.x = (t > 0.f) ? t : expm1f(t);
    t = v.y * inv + b.y; v.y = (t > 0.f) ? t : expm1f(t);
    t = v.z * inv + b.z; v.z = (t > 0.f) ? t : expm1f(t);
    t = v.w * inv + b.w; v.w = (t > 0.f) ? t : expm1f(t);
    ((float4*)acc)[idx] = v;
}

// finalize layer2: out = out/den + b2   (float4 over N*128)
__global__ void finalize2(float* __restrict__ out, const float* __restrict__ denom,
                          const float* __restrict__ bias, int n_nodes) {
    int idx = blockIdx.x * blockDim.x + threadIdx.x;
    int tot = n_nodes * 32;            // float4s per row = 32
    if (idx >= tot) return;
    int n  = idx >> 5;
    int c4 = idx & 31;
    float inv = 1.f / (denom[n] + 1e-16f);
    float4 v = ((float4*)out)[idx];
    float4 b = ((const float4*)bias)[c4];
    v.x = v.x * inv + b.x;
    v.y = v.y * inv + b.y;
    v.z = v.z * inv + b.z;
    v.w = v.w * inv + b.w;
    ((float4*)out)[idx] = v;
}

extern "C" void kernel_launch(void* const* d_in, const int* in_sizes, int n_in,
                              void* d_out, int out_size, void* d_ws, size_t ws_size,
                              hipStream_t stream) {
    const float* x    = (const float*)d_in[0];
    const int*   ei   = (const int*)d_in[1];
    const float* W1   = (const float*)d_in[2];
    const float* asr1 = (const float*)d_in[3];
    const float* ads1 = (const float*)d_in[4];
    const float* b1   = (const float*)d_in[5];
    const float* W2   = (const float*)d_in[6];
    const float* asr2 = (const float*)d_in[7];
    const float* ads2 = (const float*)d_in[8];
    const float* b2   = (const float*)d_in[9];
    float* out = (float*)d_out;

    const int N    = in_sizes[0] / IN_C;   // 50000
    const int E    = in_sizes[1] / 2;      // 500000
    const int ETOT = N + E;                // 550000

    float* ws     = (float*)d_ws;
    float* h1     = ws;                         // N*256; reused as h2 (N*128)
    float* acc1   = h1 + (size_t)N * 256;       // N*256; becomes h_elu
    float* as1    = acc1 + (size_t)N * 256;     // N*2
    float* ad1    = as1 + (size_t)N * 2;        // N*2
    float* as2    = ad1 + (size_t)N * 2;        // N
    float* ad2    = as2 + N;                    // N
    float* m1     = ad2 + N;                    // N*2
    float* m2     = m1 + (size_t)N * 2;         // N
    float* den1   = m2 + N;                     // N*2
    float* den2   = den1 + (size_t)N * 2;       // N
    float* alpha1 = den2 + N;                   // ETOT*2
    float* alpha2 = alpha1 + (size_t)ETOT * 2;  // ETOT

    // init: m1,m2 -> 0xFFFFFFFF (acts as -inf under bit-ordering); den/acc/out -> 0
    hipMemsetAsync(m1,   0xFF, (size_t)N * 3 * sizeof(float), stream);
    hipMemsetAsync(den1, 0,    (size_t)N * 3 * sizeof(float), stream);
    hipMemsetAsync(acc1, 0,    (size_t)N * 256 * sizeof(float), stream);
    hipMemsetAsync(out,  0,    (size_t)N * 128 * sizeof(float), stream);

    const int nb = (N + 31) / 32;

    // ---- layer 1 ----
    gemm_k256<256, 1><<<nb, 256, 0, stream>>>(x, W1, h1, N);
    attdots_h2<<<(N + 3) / 4, 256, 0, stream>>>(h1, asr1, ads1, as1, ad1, N);
    edge_alpha2h<<<(ETOT + 255) / 256, 256, 0, stream>>>(ei, E, ETOT, as1, ad1, alpha1, m1);
    edge_aggr_l1<<<(ETOT + 3) / 4, 256, 0, stream>>>(ei, E, ETOT, h1, alpha1, m1, den1, acc1);
    finalize1<<<((N * 64) + 255) / 256, 256, 0, stream>>>(acc1, den1, b1, N);

    // ---- layer 2 ----
    gemm_k256<128, 2><<<nb, 256, 0, stream>>>(acc1, W2, h1, N);  // h2 into h1 region
    attdots_h1<<<(N + 3) / 4, 256, 0, stream>>>(h1, asr2, ads2, as2, ad2, N);
    edge_alpha1h<<<(ETOT + 255) / 256, 256, 0, stream>>>(ei, E, ETOT, as2, ad2, alpha2, m2);
    edge_aggr_l2<<<(ETOT + 3) / 4, 256, 0, stream>>>(ei, E, ETOT, h1, alpha2, m2, den2, out);
    finalize2<<<((N * 32) + 255) / 256, 256, 0, stream>>>(out, den2, b2, N);
}

// Round 4
// 598.628 us; speedup vs baseline: 4.6899x; 4.6899x over previous
//
#include <hip/hip_runtime.h>
#include <hip/hip_bf16.h>
#include <math.h>

#define IN_C 256
#define NEG 0.2f
#define CH 256   // scan chunk size

// ---------------- GEMM:  Y[N][COLS] = X[N][256] @ W[256][COLS] ----------------
template<int COLS, int RG>
__global__ __launch_bounds__(COLS*RG) void gemm_k256(
        const float* __restrict__ X, const float* __restrict__ W,
        float* __restrict__ Y, int nrows) {
    constexpr int ROWS = 32;
    constexpr int RPT  = ROWS / RG;
    __shared__ float xs[ROWS][IN_C];
    const int tid   = threadIdx.x;
    const int rbase = blockIdx.x * ROWS;

    const int TOT4 = ROWS * IN_C / 4;
    const float4* X4 = (const float4*)(X + (size_t)rbase * IN_C);
    const int valid_rows = min(nrows - rbase, ROWS);
    const int maxi4 = valid_rows * (IN_C / 4);
    for (int i = tid; i < TOT4; i += COLS * RG) {
        float4 v = (i < maxi4) ? X4[i] : make_float4(0.f, 0.f, 0.f, 0.f);
        ((float4*)xs)[i] = v;
    }
    __syncthreads();

    const int col = tid % COLS;
    const int rg  = tid / COLS;
    float acc[RPT];
#pragma unroll
    for (int r = 0; r < RPT; ++r) acc[r] = 0.f;

    for (int k = 0; k < IN_C; k += 4) {
        float w0 = W[(size_t)(k + 0) * COLS + col];
        float w1 = W[(size_t)(k + 1) * COLS + col];
        float w2 = W[(size_t)(k + 2) * COLS + col];
        float w3 = W[(size_t)(k + 3) * COLS + col];
#pragma unroll
        for (int r = 0; r < RPT; ++r) {
            float4 xv = *(const float4*)&xs[rg * RPT + r][k];
            acc[r] = fmaf(xv.x, w0, acc[r]);
            acc[r] = fmaf(xv.y, w1, acc[r]);
            acc[r] = fmaf(xv.z, w2, acc[r]);
            acc[r] = fmaf(xv.w, w3, acc[r]);
        }
    }
#pragma unroll
    for (int r = 0; r < RPT; ++r) {
        int row = rbase + rg * RPT + r;
        if (row < nrows) Y[(size_t)row * COLS + col] = acc[r];
    }
}

// ---------------- attention dots ----------------
__global__ void attdots_h2(const float* __restrict__ H, const float* __restrict__ asrc,
                           const float* __restrict__ adst, float* __restrict__ a_s,
                           float* __restrict__ a_d, int n_nodes) {
    int node = blockIdx.x * (blockDim.x >> 6) + (threadIdx.x >> 6);
    if (node >= n_nodes) return;
    int lane = threadIdx.x & 63;
    float4 hv = ((const float4*)(H + (size_t)node * 256))[lane];
    float4 sv = ((const float4*)asrc)[lane];
    float4 dv = ((const float4*)adst)[lane];
    float ps = hv.x * sv.x + hv.y * sv.y + hv.z * sv.z + hv.w * sv.w;
    float pd = hv.x * dv.x + hv.y * dv.y + hv.z * dv.z + hv.w * dv.w;
#pragma unroll
    for (int off = 16; off; off >>= 1) {
        ps += __shfl_down(ps, off, 32);
        pd += __shfl_down(pd, off, 32);
    }
    if ((lane & 31) == 0) {
        int h = lane >> 5;
        a_s[node * 2 + h] = ps;
        a_d[node * 2 + h] = pd;
    }
}

__global__ void attdots_h1(const float* __restrict__ H, const float* __restrict__ asrc,
                           const float* __restrict__ adst, float* __restrict__ a_s,
                           float* __restrict__ a_d, int n_nodes) {
    int node = blockIdx.x * (blockDim.x >> 6) + (threadIdx.x >> 6);
    if (node >= n_nodes) return;
    int lane = threadIdx.x & 63;
    float2 hv = ((const float2*)(H + (size_t)node * 128))[lane];
    float2 sv = ((const float2*)asrc)[lane];
    float2 dv = ((const float2*)adst)[lane];
    float ps = hv.x * sv.x + hv.y * sv.y;
    float pd = hv.x * dv.x + hv.y * dv.y;
#pragma unroll
    for (int off = 32; off; off >>= 1) {
        ps += __shfl_down(ps, off, 64);
        pd += __shfl_down(pd, off, 64);
    }
    if (lane == 0) { a_s[node] = ps; a_d[node] = pd; }
}

// ---------------- CSR build (dst-indexed; self-loops implicit) ----------------
__global__ void deg_count(const int* __restrict__ ei, int E_, int* __restrict__ deg) {
    int e = blockIdx.x * blockDim.x + threadIdx.x;
    if (e < E_) atomicAdd(&deg[ei[E_ + e]], 1);
}

__global__ void chunk_reduce(const int* __restrict__ deg, int* __restrict__ csum, int n) {
    __shared__ int s[CH];
    int i = blockIdx.x * CH + threadIdx.x;
    s[threadIdx.x] = (i < n) ? deg[i] : 0;
    __syncthreads();
    for (int o = CH / 2; o; o >>= 1) {
        if (threadIdx.x < o) s[threadIdx.x] += s[threadIdx.x + o];
        __syncthreads();
    }
    if (threadIdx.x == 0) csum[blockIdx.x] = s[0];
}

// single block: exclusive scan of chunk sums (nch <= CH)
__global__ void scan_chunks(const int* __restrict__ csum, int* __restrict__ cbase, int nch) {
    __shared__ int s[CH];
    int t = threadIdx.x;
    int own = (t < nch) ? csum[t] : 0;
    s[t] = own;
    __syncthreads();
    for (int o = 1; o < CH; o <<= 1) {
        int v = (t >= o) ? s[t - o] : 0;
        __syncthreads();
        s[t] += v;
        __syncthreads();
    }
    if (t < nch) cbase[t] = s[t] - own;
}

__global__ void chunk_scan_write(const int* __restrict__ deg, const int* __restrict__ cbase,
                                 int* __restrict__ rowptr, int n) {
    __shared__ int s[CH];
    int i = blockIdx.x * CH + threadIdx.x;
    int d = (i < n) ? deg[i] : 0;
    s[threadIdx.x] = d;
    __syncthreads();
    for (int o = 1; o < CH; o <<= 1) {
        int v = (threadIdx.x >= o) ? s[threadIdx.x - o] : 0;
        __syncthreads();
        s[threadIdx.x] += v;
        __syncthreads();
    }
    if (i < n) {
        int incl = s[threadIdx.x];
        int base = cbase[blockIdx.x];
        rowptr[i] = base + incl - d;
        if (i == n - 1) rowptr[n] = base + incl;
    }
}

__global__ void csr_fill(const int* __restrict__ ei, int E_, const int* __restrict__ rowptr,
                         int* __restrict__ cursor, int* __restrict__ adj) {
    int e = blockIdx.x * blockDim.x + threadIdx.x;
    if (e >= E_) return;
    int src = ei[e], dst = ei[E_ + e];
    int pos = rowptr[dst] + atomicAdd(&cursor[dst], 1);
    adj[pos] = src;
}

// ---------------- pull-side fused aggregation ----------------
// layer 1: 2 heads x 128; out = elu(softmax-weighted sum / den + bias)
__global__ void aggr_l1(const int* __restrict__ rowptr, const int* __restrict__ adj,
                        const float* __restrict__ H, const float* __restrict__ a_s,
                        const float* __restrict__ a_d, const float* __restrict__ bias,
                        float* __restrict__ out, int n_nodes) {
    int node = blockIdx.x * (blockDim.x >> 6) + (threadIdx.x >> 6);
    if (node >= n_nodes) return;
    int lane = threadIdx.x & 63;
    int h = lane >> 5;
    int beg = rowptr[node], end = rowptr[node + 1];
    float ad = a_d[node * 2 + h];

    // pass 1: segment max (self-loop included)
    float vself = a_s[node * 2 + h] + ad;
    vself = (vself > 0.f) ? vself : NEG * vself;
    float m = vself;
    for (int i = beg; i < end; ++i) {
        int s = adj[i];
        float t = a_s[s * 2 + h] + ad;
        t = (t > 0.f) ? t : NEG * t;
        m = fmaxf(m, t);
    }

    // pass 2: accumulate
    float den = __expf(vself - m);
    float4 hv = ((const float4*)(H + (size_t)node * 256))[lane];
    float4 acc = make_float4(hv.x * den, hv.y * den, hv.z * den, hv.w * den);
    for (int i = beg; i < end; ++i) {
        int s = adj[i];
        float t = a_s[s * 2 + h] + ad;
        t = (t > 0.f) ? t : NEG * t;
        float ev = __expf(t - m);
        den += ev;
        float4 x = ((const float4*)(H + (size_t)s * 256))[lane];
        acc.x = fmaf(x.x, ev, acc.x);
        acc.y = fmaf(x.y, ev, acc.y);
        acc.z = fmaf(x.z, ev, acc.z);
        acc.w = fmaf(x.w, ev, acc.w);
    }
    float inv = 1.f / (den + 1e-16f);
    float4 b = ((const float4*)bias)[lane];
    float t0;
    t0 = acc.x * inv + b.x; acc.x = (t0 > 0.f) ? t0 : expm1f(t0);
    t0 = acc.y * inv + b.y; acc.y = (t0 > 0.f) ? t0 : expm1f(t0);
    t0 = acc.z * inv + b.z; acc.z = (t0 > 0.f) ? t0 : expm1f(t0);
    t0 = acc.w * inv + b.w; acc.w = (t0 > 0.f) ? t0 : expm1f(t0);
    ((float4*)(out + (size_t)node * 256))[lane] = acc;
}

// layer 2: 1 head x 128; out = weighted sum / den + bias (no ELU)
__global__ void aggr_l2(const int* __restrict__ rowptr, const int* __restrict__ adj,
                        const float* __restrict__ H, const float* __restrict__ a_s,
                        const float* __restrict__ a_d, const float* __restrict__ bias,
                        float* __restrict__ out, int n_nodes) {
    int node = blockIdx.x * (blockDim.x >> 6) + (threadIdx.x >> 6);
    if (node >= n_nodes) return;
    int lane = threadIdx.x & 63;
    int beg = rowptr[node], end = rowptr[node + 1];
    float ad = a_d[node];

    float vself = a_s[node] + ad;
    vself = (vself > 0.f) ? vself : NEG * vself;
    float m = vself;
    for (int i = beg; i < end; ++i) {
        int s = adj[i];
        float t = a_s[s] + ad;
        t = (t > 0.f) ? t : NEG * t;
        m = fmaxf(m, t);
    }

    float den = __expf(vself - m);
    float2 hv = ((const float2*)(H + (size_t)node * 128))[lane];
    float2 acc = make_float2(hv.x * den, hv.y * den);
    for (int i = beg; i < end; ++i) {
        int s = adj[i];
        float t = a_s[s] + ad;
        t = (t > 0.f) ? t : NEG * t;
        float ev = __expf(t - m);
        den += ev;
        float2 x = ((const float2*)(H + (size_t)s * 128))[lane];
        acc.x = fmaf(x.x, ev, acc.x);
        acc.y = fmaf(x.y, ev, acc.y);
    }
    float inv = 1.f / (den + 1e-16f);
    float2 b = ((const float2*)bias)[lane];
    acc.x = acc.x * inv + b.x;
    acc.y = acc.y * inv + b.y;
    ((float2*)(out + (size_t)node * 128))[lane] = acc;
}

extern "C" void kernel_launch(void* const* d_in, const int* in_sizes, int n_in,
                              void* d_out, int out_size, void* d_ws, size_t ws_size,
                              hipStream_t stream) {
    const float* x    = (const float*)d_in[0];
    const int*   ei   = (const int*)d_in[1];
    const float* W1   = (const float*)d_in[2];
    const float* asr1 = (const float*)d_in[3];
    const float* ads1 = (const float*)d_in[4];
    const float* b1   = (const float*)d_in[5];
    const float* W2   = (const float*)d_in[6];
    const float* asr2 = (const float*)d_in[7];
    const float* ads2 = (const float*)d_in[8];
    const float* b2   = (const float*)d_in[9];
    float* out = (float*)d_out;

    const int N = in_sizes[0] / IN_C;   // 50000
    const int E = in_sizes[1] / 2;      // 500000
    const int NCH = (N + CH - 1) / CH;  // 196

    float* ws   = (float*)d_ws;
    float* h1   = ws;                        // N*256 (also reused as h2: N*128)
    float* helu = h1 + (size_t)N * 256;      // N*256
    float* as1  = helu + (size_t)N * 256;    // 2N
    float* ad1  = as1 + (size_t)N * 2;       // 2N
    float* as2  = ad1 + (size_t)N * 2;       // N
    float* ad2  = as2 + N;                   // N
    int* rowptr = (int*)(ad2 + N);           // N+1
    int* deg    = rowptr + (N + 1);          // N
    int* cursor = deg + N;                   // N
    int* csum   = cursor + N;                // NCH
    int* cbase  = csum + NCH;                // NCH
    int* adj    = cbase + NCH;               // E

    // zero the CSR counters (ws is poisoned 0xAA before every timed launch)
    hipMemsetAsync(deg,    0, (size_t)N * sizeof(int), stream);
    hipMemsetAsync(cursor, 0, (size_t)N * sizeof(int), stream);

    const int nb = (N + 31) / 32;

    // CSR build (graph shared by both layers)
    deg_count<<<(E + 255) / 256, 256, 0, stream>>>(ei, E, deg);
    chunk_reduce<<<NCH, CH, 0, stream>>>(deg, csum, N);
    scan_chunks<<<1, CH, 0, stream>>>(csum, cbase, NCH);
    chunk_scan_write<<<NCH, CH, 0, stream>>>(deg, cbase, rowptr, N);
    csr_fill<<<(E + 255) / 256, 256, 0, stream>>>(ei, E, rowptr, cursor, adj);

    // ---- layer 1 ----
    gemm_k256<256, 1><<<nb, 256, 0, stream>>>(x, W1, h1, N);
    attdots_h2<<<(N + 3) / 4, 256, 0, stream>>>(h1, asr1, ads1, as1, ad1, N);
    aggr_l1<<<(N + 3) / 4, 256, 0, stream>>>(rowptr, adj, h1, as1, ad1, b1, helu, N);

    // ---- layer 2 ----
    gemm_k256<128, 2><<<nb, 256, 0, stream>>>(helu, W2, h1, N);   // h2 into h1 region
    attdots_h1<<<(N + 3) / 4, 256, 0, stream>>>(h1, asr2, ads2, as2, ad2, N);
    aggr_l2<<<(N + 3) / 4, 256, 0, stream>>>(rowptr, adj, h1, as2, ad2, b2, out, N);
}

// Round 16
// 448.153 us; speedup vs baseline: 6.2646x; 1.3358x over previous
//
#include <hip/hip_runtime.h>
#include <hip/hip_bf16.h>
#include <math.h>

#define IN_C 256
#define NEG 0.2f
#define CH 256   // scan chunk size

typedef __attribute__((ext_vector_type(8))) short bf16x8s;  // 8 bf16 (4 VGPRs)
typedef __attribute__((ext_vector_type(4))) float f32x4;

// ---------------- fp32 -> bf16 convert (row-major) ----------------
__global__ void f2b(const float4* __restrict__ in, ushort4* __restrict__ out, int n4) {
    int i = blockIdx.x * blockDim.x + threadIdx.x;
    if (i >= n4) return;
    float4 v = in[i];
    union { ushort4 u; __hip_bfloat16 b[4]; } cv;
    cv.b[0] = __float2bfloat16(v.x);
    cv.b[1] = __float2bfloat16(v.y);
    cv.b[2] = __float2bfloat16(v.z);
    cv.b[3] = __float2bfloat16(v.w);
    out[i] = cv.u;
}

// ---------------- pack W[K=256][COLS] into MFMA B-frag order ----------------
// Wp[((s*(COLS/16)+t)*64 + lane)*8 + i] = W[s*32 + (lane>>4)*8 + i][t*16 + (lane&15)]
template<int COLS>
__global__ void pack_w(const float* __restrict__ W, __hip_bfloat16* __restrict__ Wp) {
    int idx = blockIdx.x * blockDim.x + threadIdx.x;     // one thread per (s,t,lane)
    constexpr int NT = COLS / 16;
    if (idx >= 8 * NT * 64) return;
    int lane = idx & 63;
    int t    = (idx >> 6) % NT;
    int s    = (idx >> 6) / NT;
    int kbase = s * 32 + (lane >> 4) * 8;
    int c     = t * 16 + (lane & 15);
#pragma unroll
    for (int i = 0; i < 8; ++i)
        Wp[(size_t)idx * 8 + i] = __float2bfloat16(W[(size_t)(kbase + i) * COLS + c]);
}

// ---------------- MFMA GEMM: Y[M][NT*16] = Xb[M][256] @ W ----------------
// 4 waves/block; each wave: 16 rows x NT*16 cols, K=256 in 8 steps.
template<int NT>
__global__ __launch_bounds__(256) void gemm_mfma(
        const __hip_bfloat16* __restrict__ Xb, const __hip_bfloat16* __restrict__ Wp,
        float* __restrict__ Y, int nrows) {
    const int wave = threadIdx.x >> 6;
    const int lane = threadIdx.x & 63;
    const int rbase = (blockIdx.x * 4 + wave) * 16;
    if (rbase >= nrows) return;
    const int l15 = lane & 15, lhi = lane >> 4;

    f32x4 acc[NT];
#pragma unroll
    for (int t = 0; t < NT; ++t) acc[t] = (f32x4){0.f, 0.f, 0.f, 0.f};

    const __hip_bfloat16* aptr = Xb + (size_t)(rbase + l15) * 256 + lhi * 8;
    const __hip_bfloat16* wptr = Wp + (size_t)lane * 8;

#pragma unroll
    for (int s = 0; s < 8; ++s) {
        bf16x8s a = *(const bf16x8s*)(aptr + s * 32);
#pragma unroll
        for (int t = 0; t < NT; ++t) {
            bf16x8s b = *(const bf16x8s*)(wptr + (size_t)(s * NT + t) * 512);
            acc[t] = __builtin_amdgcn_mfma_f32_16x16x32_bf16(a, b, acc[t], 0, 0, 0);
        }
    }
    // C layout: row = rbase + lhi*4 + r, col = t*16 + l15
#pragma unroll
    for (int t = 0; t < NT; ++t)
#pragma unroll
        for (int r = 0; r < 4; ++r)
            Y[(size_t)(rbase + lhi * 4 + r) * (NT * 16) + t * 16 + l15] = acc[t][r];
}

// ---------------- attention dots ----------------
__global__ void attdots_h2(const float* __restrict__ H, const float* __restrict__ asrc,
                           const float* __restrict__ adst, float* __restrict__ a_s,
                           float* __restrict__ a_d, int n_nodes) {
    int node = blockIdx.x * (blockDim.x >> 6) + (threadIdx.x >> 6);
    if (node >= n_nodes) return;
    int lane = threadIdx.x & 63;
    float4 hv = ((const float4*)(H + (size_t)node * 256))[lane];
    float4 sv = ((const float4*)asrc)[lane];
    float4 dv = ((const float4*)adst)[lane];
    float ps = hv.x * sv.x + hv.y * sv.y + hv.z * sv.z + hv.w * sv.w;
    float pd = hv.x * dv.x + hv.y * dv.y + hv.z * dv.z + hv.w * dv.w;
#pragma unroll
    for (int off = 16; off; off >>= 1) {
        ps += __shfl_down(ps, off, 32);
        pd += __shfl_down(pd, off, 32);
    }
    if ((lane & 31) == 0) {
        int h = lane >> 5;
        a_s[node * 2 + h] = ps;
        a_d[node * 2 + h] = pd;
    }
}

__global__ void attdots_h1(const float* __restrict__ H, const float* __restrict__ asrc,
                           const float* __restrict__ adst, float* __restrict__ a_s,
                           float* __restrict__ a_d, int n_nodes) {
    int node = blockIdx.x * (blockDim.x >> 6) + (threadIdx.x >> 6);
    if (node >= n_nodes) return;
    int lane = threadIdx.x & 63;
    float2 hv = ((const float2*)(H + (size_t)node * 128))[lane];
    float2 sv = ((const float2*)asrc)[lane];
    float2 dv = ((const float2*)adst)[lane];
    float ps = hv.x * sv.x + hv.y * sv.y;
    float pd = hv.x * dv.x + hv.y * dv.y;
#pragma unroll
    for (int off = 32; off; off >>= 1) {
        ps += __shfl_down(ps, off, 64);
        pd += __shfl_down(pd, off, 64);
    }
    if (lane == 0) { a_s[node] = ps; a_d[node] = pd; }
}

// ---------------- CSR build (dst-indexed; self-loops implicit) ----------------
__global__ void deg_count(const int* __restrict__ ei, int E_, int* __restrict__ deg) {
    int e = blockIdx.x * blockDim.x + threadIdx.x;
    if (e < E_) atomicAdd(&deg[ei[E_ + e]], 1);
}

__global__ void chunk_reduce(const int* __restrict__ deg, int* __restrict__ csum, int n) {
    __shared__ int s[CH];
    int i = blockIdx.x * CH + threadIdx.x;
    s[threadIdx.x] = (i < n) ? deg[i] : 0;
    __syncthreads();
    for (int o = CH / 2; o; o >>= 1) {
        if (threadIdx.x < o) s[threadIdx.x] += s[threadIdx.x + o];
        __syncthreads();
    }
    if (threadIdx.x == 0) csum[blockIdx.x] = s[0];
}

__global__ void scan_chunks(const int* __restrict__ csum, int* __restrict__ cbase, int nch) {
    __shared__ int s[CH];
    int t = threadIdx.x;
    int own = (t < nch) ? csum[t] : 0;
    s[t] = own;
    __syncthreads();
    for (int o = 1; o < CH; o <<= 1) {
        int v = (t >= o) ? s[t - o] : 0;
        __syncthreads();
        s[t] += v;
        __syncthreads();
    }
    if (t < nch) cbase[t] = s[t] - own;
}

__global__ void chunk_scan_write(const int* __restrict__ deg, const int* __restrict__ cbase,
                                 int* __restrict__ rowptr, int n) {
    __shared__ int s[CH];
    int i = blockIdx.x * CH + threadIdx.x;
    int d = (i < n) ? deg[i] : 0;
    s[threadIdx.x] = d;
    __syncthreads();
    for (int o = 1; o < CH; o <<= 1) {
        int v = (threadIdx.x >= o) ? s[threadIdx.x - o] : 0;
        __syncthreads();
        s[threadIdx.x] += v;
        __syncthreads();
    }
    if (i < n) {
        int incl = s[threadIdx.x];
        int base = cbase[blockIdx.x];
        rowptr[i] = base + incl - d;
        if (i == n - 1) rowptr[n] = base + incl;
    }
}

__global__ void csr_fill(const int* __restrict__ ei, int E_, const int* __restrict__ rowptr,
                         int* __restrict__ cursor, int* __restrict__ adj) {
    int e = blockIdx.x * blockDim.x + threadIdx.x;
    if (e >= E_) return;
    int src = ei[e], dst = ei[E_ + e];
    int pos = rowptr[dst] + atomicAdd(&cursor[dst], 1);
    adj[pos] = src;
}

// ---------------- pull-side fused aggregation ----------------
// layer 1: 2 heads x 128; out = elu(sum/den + bias), written in BF16 (feeds GEMM2)
__global__ void aggr_l1(const int* __restrict__ rowptr, const int* __restrict__ adj,
                        const float* __restrict__ H, const float* __restrict__ a_s,
                        const float* __restrict__ a_d, const float* __restrict__ bias,
                        __hip_bfloat16* __restrict__ out, int n_nodes) {
    int node = blockIdx.x * (blockDim.x >> 6) + (threadIdx.x >> 6);
    if (node >= n_nodes) return;
    int lane = threadIdx.x & 63;
    int h = lane >> 5;
    int beg = rowptr[node], end = rowptr[node + 1];
    float ad = a_d[node * 2 + h];

    float vself = a_s[node * 2 + h] + ad;
    vself = (vself > 0.f) ? vself : NEG * vself;
    float m = vself;
    for (int i = beg; i < end; ++i) {
        int s = adj[i];
        float t = a_s[s * 2 + h] + ad;
        t = (t > 0.f) ? t : NEG * t;
        m = fmaxf(m, t);
    }

    float den = __expf(vself - m);
    float4 hv = ((const float4*)(H + (size_t)node * 256))[lane];
    float4 acc = make_float4(hv.x * den, hv.y * den, hv.z * den, hv.w * den);
    for (int i = beg; i < end; ++i) {
        int s = adj[i];
        float t = a_s[s * 2 + h] + ad;
        t = (t > 0.f) ? t : NEG * t;
        float ev = __expf(t - m);
        den += ev;
        float4 x = ((const float4*)(H + (size_t)s * 256))[lane];
        acc.x = fmaf(x.x, ev, acc.x);
        acc.y = fmaf(x.y, ev, acc.y);
        acc.z = fmaf(x.z, ev, acc.z);
        acc.w = fmaf(x.w, ev, acc.w);
    }
    float inv = 1.f / (den + 1e-16f);
    float4 b = ((const float4*)bias)[lane];
    float t0;
    union { ushort4 u; __hip_bfloat16 bb[4]; } cv;
    t0 = acc.x * inv + b.x; cv.bb[0] = __float2bfloat16((t0 > 0.f) ? t0 : expm1f(t0));
    t0 = acc.y * inv + b.y; cv.bb[1] = __float2bfloat16((t0 > 0.f) ? t0 : expm1f(t0));
    t0 = acc.z * inv + b.z; cv.bb[2] = __float2bfloat16((t0 > 0.f) ? t0 : expm1f(t0));
    t0 = acc.w * inv + b.w; cv.bb[3] = __float2bfloat16((t0 > 0.f) ? t0 : expm1f(t0));
    ((ushort4*)(out + (size_t)node * 256))[lane] = cv.u;
}

// layer 2: 1 head x 128; out = sum/den + bias (fp32)
__global__ void aggr_l2(const int* __restrict__ rowptr, const int* __restrict__ adj,
                        const float* __restrict__ H, const float* __restrict__ a_s,
                        const float* __restrict__ a_d, const float* __restrict__ bias,
                        float* __restrict__ out, int n_nodes) {
    int node = blockIdx.x * (blockDim.x >> 6) + (threadIdx.x >> 6);
    if (node >= n_nodes) return;
    int lane = threadIdx.x & 63;
    int beg = rowptr[node], end = rowptr[node + 1];
    float ad = a_d[node];

    float vself = a_s[node] + ad;
    vself = (vself > 0.f) ? vself : NEG * vself;
    float m = vself;
    for (int i = beg; i < end; ++i) {
        int s = adj[i];
        float t = a_s[s] + ad;
        t = (t > 0.f) ? t : NEG * t;
        m = fmaxf(m, t);
    }

    float den = __expf(vself - m);
    float2 hv = ((const float2*)(H + (size_t)node * 128))[lane];
    float2 acc = make_float2(hv.x * den, hv.y * den);
    for (int i = beg; i < end; ++i) {
        int s = adj[i];
        float t = a_s[s] + ad;
        t = (t > 0.f) ? t : NEG * t;
        float ev = __expf(t - m);
        den += ev;
        float2 x = ((const float2*)(H + (size_t)s * 128))[lane];
        acc.x = fmaf(x.x, ev, acc.x);
        acc.y = fmaf(x.y, ev, acc.y);
    }
    float inv = 1.f / (den + 1e-16f);
    float2 b = ((const float2*)bias)[lane];
    acc.x = acc.x * inv + b.x;
    acc.y = acc.y * inv + b.y;
    ((float2*)(out + (size_t)node * 128))[lane] = acc;
}

extern "C" void kernel_launch(void* const* d_in, const int* in_sizes, int n_in,
                              void* d_out, int out_size, void* d_ws, size_t ws_size,
                              hipStream_t stream) {
    const float* x    = (const float*)d_in[0];
    const int*   ei   = (const int*)d_in[1];
    const float* W1   = (const float*)d_in[2];
    const float* asr1 = (const float*)d_in[3];
    const float* ads1 = (const float*)d_in[4];
    const float* b1   = (const float*)d_in[5];
    const float* W2   = (const float*)d_in[6];
    const float* asr2 = (const float*)d_in[7];
    const float* ads2 = (const float*)d_in[8];
    const float* b2   = (const float*)d_in[9];
    float* out = (float*)d_out;

    const int N = in_sizes[0] / IN_C;   // 50000
    const int E = in_sizes[1] / 2;      // 500000
    const int NCH = (N + CH - 1) / CH;  // 196

    float* ws = (float*)d_ws;
    float* h1 = ws;                                   // N*256 f32 (later reused as h2: N*128 f32)
    float* h2 = h1;                                   // alias (h1 dead after aggr_l1)
    __hip_bfloat16* xb  = (__hip_bfloat16*)(h1 + (size_t)N * 256);   // N*256 bf16
    __hip_bfloat16* hel = xb + (size_t)N * 256;                      // N*256 bf16
    float* as1 = (float*)(hel + (size_t)N * 256);     // 2N
    float* ad1 = as1 + (size_t)N * 2;                 // 2N
    float* as2 = ad1 + (size_t)N * 2;                 // N
    float* ad2 = as2 + N;                             // N
    int* rowptr = (int*)(ad2 + N);                    // N+1
    int* deg    = rowptr + (N + 1);                   // N
    int* cursor = deg + N;                            // N
    int* csum   = cursor + N;                         // NCH
    int* cbase  = csum + NCH;                         // NCH
    int* adjl   = cbase + NCH;                        // E
    __hip_bfloat16* Wp1 = (__hip_bfloat16*)(adjl + E);   // 8*16*64*8 = 65536
    __hip_bfloat16* Wp2 = Wp1 + 65536;                   // 8*8*64*8  = 32768

    hipMemsetAsync(deg,    0, (size_t)N * sizeof(int), stream);
    hipMemsetAsync(cursor, 0, (size_t)N * sizeof(int), stream);

    // CSR build
    deg_count<<<(E + 255) / 256, 256, 0, stream>>>(ei, E, deg);
    chunk_reduce<<<NCH, CH, 0, stream>>>(deg, csum, N);
    scan_chunks<<<1, CH, 0, stream>>>(csum, cbase, NCH);
    chunk_scan_write<<<NCH, CH, 0, stream>>>(deg, cbase, rowptr, N);
    csr_fill<<<(E + 255) / 256, 256, 0, stream>>>(ei, E, rowptr, cursor, adjl);

    // weight pack + x convert
    pack_w<256><<<(8 * 16 * 64 + 255) / 256, 256, 0, stream>>>(W1, Wp1);
    pack_w<128><<<(8 * 8 * 64 + 255) / 256, 256, 0, stream>>>(W2, Wp2);
    f2b<<<((N * 64) + 255) / 256, 256, 0, stream>>>((const float4*)x, (ushort4*)xb, N * 64);

    const int gb = ((N + 15) / 16 + 3) / 4;   // row-tiles / 4 waves

    // ---- layer 1 ----
    gemm_mfma<16><<<gb, 256, 0, stream>>>(xb, Wp1, h1, N);
    attdots_h2<<<(N + 3) / 4, 256, 0, stream>>>(h1, asr1, ads1, as1, ad1, N);
    aggr_l1<<<(N + 3) / 4, 256, 0, stream>>>(rowptr, adjl, h1, as1, ad1, b1, hel, N);

    // ---- layer 2 ----
    gemm_mfma<8><<<gb, 256, 0, stream>>>(hel, Wp2, h2, N);
    attdots_h1<<<(N + 3) / 4, 256, 0, stream>>>(h2, asr2, ads2, as2, ad2, N);
    aggr_l2<<<(N + 3) / 4, 256, 0, stream>>>(rowptr, adjl, h2, as2, ad2, b2, out, N);
}

// Round 18
// 431.620 us; speedup vs baseline: 6.5046x; 1.0383x over previous
//
#include <hip/hip_runtime.h>
#include <hip/hip_bf16.h>
#include <math.h>

#define IN_C 256
#define NEG 0.2f
#define CH 256   // scan chunk size

typedef __attribute__((ext_vector_type(8))) short bf16x8s;  // 8 bf16 (4 VGPRs)
typedef __attribute__((ext_vector_type(4))) float f32x4;

__device__ __forceinline__ float b2f(ushort u) {
    union { unsigned int i; float f; } c;
    c.i = ((unsigned int)u) << 16;
    return c.f;
}

// ---------------- fp32 -> bf16 convert (row-major) ----------------
__global__ void f2b(const float4* __restrict__ in, ushort4* __restrict__ out, int n4) {
    int i = blockIdx.x * blockDim.x + threadIdx.x;
    if (i >= n4) return;
    float4 v = in[i];
    union { ushort4 u; __hip_bfloat16 b[4]; } cv;
    cv.b[0] = __float2bfloat16(v.x);
    cv.b[1] = __float2bfloat16(v.y);
    cv.b[2] = __float2bfloat16(v.z);
    cv.b[3] = __float2bfloat16(v.w);
    out[i] = cv.u;
}

// ---------------- pack W[K=256][COLS] into MFMA B-frag order ----------------
template<int COLS>
__global__ void pack_w(const float* __restrict__ W, __hip_bfloat16* __restrict__ Wp) {
    int idx = blockIdx.x * blockDim.x + threadIdx.x;
    constexpr int NT = COLS / 16;
    if (idx >= 8 * NT * 64) return;
    int lane = idx & 63;
    int t    = (idx >> 6) % NT;
    int s    = (idx >> 6) / NT;
    int kbase = s * 32 + (lane >> 4) * 8;
    int c     = t * 16 + (lane & 15);
#pragma unroll
    for (int i = 0; i < 8; ++i)
        Wp[(size_t)idx * 8 + i] = __float2bfloat16(W[(size_t)(kbase + i) * COLS + c]);
}

// ---------------- MFMA GEMM: Yb[M][NT*16] = Xb[M][256] @ W  (bf16 out) ----------------
template<int NT>
__global__ __launch_bounds__(256) void gemm_mfma(
        const __hip_bfloat16* __restrict__ Xb, const __hip_bfloat16* __restrict__ Wp,
        __hip_bfloat16* __restrict__ Y, int nrows) {
    const int wave = threadIdx.x >> 6;
    const int lane = threadIdx.x & 63;
    const int rbase = (blockIdx.x * 4 + wave) * 16;
    if (rbase >= nrows) return;
    const int l15 = lane & 15, lhi = lane >> 4;

    f32x4 acc[NT];
#pragma unroll
    for (int t = 0; t < NT; ++t) acc[t] = (f32x4){0.f, 0.f, 0.f, 0.f};

    const __hip_bfloat16* aptr = Xb + (size_t)(rbase + l15) * 256 + lhi * 8;
    const __hip_bfloat16* wptr = Wp + (size_t)lane * 8;

#pragma unroll
    for (int s = 0; s < 8; ++s) {
        bf16x8s a = *(const bf16x8s*)(aptr + s * 32);
#pragma unroll
        for (int t = 0; t < NT; ++t) {
            bf16x8s b = *(const bf16x8s*)(wptr + (size_t)(s * NT + t) * 512);
            acc[t] = __builtin_amdgcn_mfma_f32_16x16x32_bf16(a, b, acc[t], 0, 0, 0);
        }
    }
    // C layout: row = rbase + lhi*4 + r, col = t*16 + l15
#pragma unroll
    for (int t = 0; t < NT; ++t)
#pragma unroll
        for (int r = 0; r < 4; ++r)
            Y[(size_t)(rbase + lhi * 4 + r) * (NT * 16) + t * 16 + l15] =
                __float2bfloat16(acc[t][r]);
}

// ---------------- attention dots (bf16 H) ----------------
__global__ void attdots_h2(const __hip_bfloat16* __restrict__ H, const float* __restrict__ asrc,
                           const float* __restrict__ adst, float* __restrict__ a_s,
                           float* __restrict__ a_d, int n_nodes) {
    int node = blockIdx.x * (blockDim.x >> 6) + (threadIdx.x >> 6);
    if (node >= n_nodes) return;
    int lane = threadIdx.x & 63;
    ushort4 hv = ((const ushort4*)(H + (size_t)node * 256))[lane];
    float4 sv = ((const float4*)asrc)[lane];
    float4 dv = ((const float4*)adst)[lane];
    float h0 = b2f(hv.x), h1 = b2f(hv.y), h2 = b2f(hv.z), h3 = b2f(hv.w);
    float ps = h0 * sv.x + h1 * sv.y + h2 * sv.z + h3 * sv.w;
    float pd = h0 * dv.x + h1 * dv.y + h2 * dv.z + h3 * dv.w;
#pragma unroll
    for (int off = 16; off; off >>= 1) {
        ps += __shfl_down(ps, off, 32);
        pd += __shfl_down(pd, off, 32);
    }
    if ((lane & 31) == 0) {
        int h = lane >> 5;
        a_s[node * 2 + h] = ps;
        a_d[node * 2 + h] = pd;
    }
}

__global__ void attdots_h1(const __hip_bfloat16* __restrict__ H, const float* __restrict__ asrc,
                           const float* __restrict__ adst, float* __restrict__ a_s,
                           float* __restrict__ a_d, int n_nodes) {
    int node = blockIdx.x * (blockDim.x >> 6) + (threadIdx.x >> 6);
    if (node >= n_nodes) return;
    int lane = threadIdx.x & 63;
    ushort2 hv = ((const ushort2*)(H + (size_t)node * 128))[lane];
    float2 sv = ((const float2*)asrc)[lane];
    float2 dv = ((const float2*)adst)[lane];
    float h0 = b2f(hv.x), h1 = b2f(hv.y);
    float ps = h0 * sv.x + h1 * sv.y;
    float pd = h0 * dv.x + h1 * dv.y;
#pragma unroll
    for (int off = 32; off; off >>= 1) {
        ps += __shfl_down(ps, off, 64);
        pd += __shfl_down(pd, off, 64);
    }
    if (lane == 0) { a_s[node] = ps; a_d[node] = pd; }
}

// ---------------- CSR build (dst-indexed; self-loops implicit) ----------------
__global__ void deg_count(const int* __restrict__ ei, int E_, int* __restrict__ deg) {
    int e = blockIdx.x * blockDim.x + threadIdx.x;
    if (e < E_) atomicAdd(&deg[ei[E_ + e]], 1);
}

__global__ void chunk_reduce(const int* __restrict__ deg, int* __restrict__ csum, int n) {
    __shared__ int s[CH];
    int i = blockIdx.x * CH + threadIdx.x;
    s[threadIdx.x] = (i < n) ? deg[i] : 0;
    __syncthreads();
    for (int o = CH / 2; o; o >>= 1) {
        if (threadIdx.x < o) s[threadIdx.x] += s[threadIdx.x + o];
        __syncthreads();
    }
    if (threadIdx.x == 0) csum[blockIdx.x] = s[0];
}

__global__ void scan_chunks(const int* __restrict__ csum, int* __restrict__ cbase, int nch) {
    __shared__ int s[CH];
    int t = threadIdx.x;
    int own = (t < nch) ? csum[t] : 0;
    s[t] = own;
    __syncthreads();
    for (int o = 1; o < CH; o <<= 1) {
        int v = (t >= o) ? s[t - o] : 0;
        __syncthreads();
        s[t] += v;
        __syncthreads();
    }
    if (t < nch) cbase[t] = s[t] - own;
}

__global__ void chunk_scan_write(const int* __restrict__ deg, const int* __restrict__ cbase,
                                 int* __restrict__ rowptr, int n) {
    __shared__ int s[CH];
    int i = blockIdx.x * CH + threadIdx.x;
    int d = (i < n) ? deg[i] : 0;
    s[threadIdx.x] = d;
    __syncthreads();
    for (int o = 1; o < CH; o <<= 1) {
        int v = (threadIdx.x >= o) ? s[threadIdx.x - o] : 0;
        __syncthreads();
        s[threadIdx.x] += v;
        __syncthreads();
    }
    if (i < n) {
        int incl = s[threadIdx.x];
        int base = cbase[blockIdx.x];
        rowptr[i] = base + incl - d;
        if (i == n - 1) rowptr[n] = base + incl;
    }
}

__global__ void csr_fill(const int* __restrict__ ei, int E_, const int* __restrict__ rowptr,
                         int* __restrict__ cursor, int* __restrict__ adj) {
    int e = blockIdx.x * blockDim.x + threadIdx.x;
    if (e >= E_) return;
    int src = ei[e], dst = ei[E_ + e];
    int pos = rowptr[dst] + atomicAdd(&cursor[dst], 1);
    adj[pos] = src;
}

// ---------------- pull-side fused aggregation (bf16 H gather) ----------------
// layer 1: 2 heads x 128; out = elu(sum/den + bias) -> bf16 (feeds GEMM2)
__global__ void aggr_l1(const int* __restrict__ rowptr, const int* __restrict__ adj,
                        const __hip_bfloat16* __restrict__ H, const float* __restrict__ a_s,
                        const float* __restrict__ a_d, const float* __restrict__ bias,
                        __hip_bfloat16* __restrict__ out, int n_nodes) {
    int node = blockIdx.x * (blockDim.x >> 6) + (threadIdx.x >> 6);
    if (node >= n_nodes) return;
    int lane = threadIdx.x & 63;
    int h = lane >> 5;
    int beg = rowptr[node], end = rowptr[node + 1];
    float ad = a_d[node * 2 + h];

    float vself = a_s[node * 2 + h] + ad;
    vself = (vself > 0.f) ? vself : NEG * vself;
    float m = vself;
    for (int i = beg; i < end; ++i) {
        int s = adj[i];
        float t = a_s[s * 2 + h] + ad;
        t = (t > 0.f) ? t : NEG * t;
        m = fmaxf(m, t);
    }

    float den = __expf(vself - m);
    ushort4 hv = ((const ushort4*)(H + (size_t)node * 256))[lane];
    float4 acc = make_float4(b2f(hv.x) * den, b2f(hv.y) * den,
                             b2f(hv.z) * den, b2f(hv.w) * den);
    for (int i = beg; i < end; ++i) {
        int s = adj[i];
        float t = a_s[s * 2 + h] + ad;
        t = (t > 0.f) ? t : NEG * t;
        float ev = __expf(t - m);
        den += ev;
        ushort4 x = ((const ushort4*)(H + (size_t)s * 256))[lane];
        acc.x = fmaf(b2f(x.x), ev, acc.x);
        acc.y = fmaf(b2f(x.y), ev, acc.y);
        acc.z = fmaf(b2f(x.z), ev, acc.z);
        acc.w = fmaf(b2f(x.w), ev, acc.w);
    }
    float inv = 1.f / (den + 1e-16f);
    float4 b = ((const float4*)bias)[lane];
    float t0;
    union { ushort4 u; __hip_bfloat16 bb[4]; } cv;
    t0 = acc.x * inv + b.x; cv.bb[0] = __float2bfloat16((t0 > 0.f) ? t0 : expm1f(t0));
    t0 = acc.y * inv + b.y; cv.bb[1] = __float2bfloat16((t0 > 0.f) ? t0 : expm1f(t0));
    t0 = acc.z * inv + b.z; cv.bb[2] = __float2bfloat16((t0 > 0.f) ? t0 : expm1f(t0));
    t0 = acc.w * inv + b.w; cv.bb[3] = __float2bfloat16((t0 > 0.f) ? t0 : expm1f(t0));
    ((ushort4*)(out + (size_t)node * 256))[lane] = cv.u;
}

// layer 2: 1 head x 128; out = sum/den + bias (fp32 final)
__global__ void aggr_l2(const int* __restrict__ rowptr, const int* __restrict__ adj,
                        const __hip_bfloat16* __restrict__ H, const float* __restrict__ a_s,
                        const float* __restrict__ a_d, const float* __restrict__ bias,
                        float* __restrict__ out, int n_nodes) {
    int node = blockIdx.x * (blockDim.x >> 6) + (threadIdx.x >> 6);
    if (node >= n_nodes) return;
    int lane = threadIdx.x & 63;
    int beg = rowptr[node], end = rowptr[node + 1];
    float ad = a_d[node];

    float vself = a_s[node] + ad;
    vself = (vself > 0.f) ? vself : NEG * vself;
    float m = vself;
    for (int i = beg; i < end; ++i) {
        int s = adj[i];
        float t = a_s[s] + ad;
        t = (t > 0.f) ? t : NEG * t;
        m = fmaxf(m, t);
    }

    float den = __expf(vself - m);
    ushort2 hv = ((const ushort2*)(H + (size_t)node * 128))[lane];
    float2 acc = make_float2(b2f(hv.x) * den, b2f(hv.y) * den);
    for (int i = beg; i < end; ++i) {
        int s = adj[i];
        float t = a_s[s] + ad;
        t = (t > 0.f) ? t : NEG * t;
        float ev = __expf(t - m);
        den += ev;
        ushort2 x = ((const ushort2*)(H + (size_t)s * 128))[lane];
        acc.x = fmaf(b2f(x.x), ev, acc.x);
        acc.y = fmaf(b2f(x.y), ev, acc.y);
    }
    float inv = 1.f / (den + 1e-16f);
    float2 b = ((const float2*)bias)[lane];
    acc.x = acc.x * inv + b.x;
    acc.y = acc.y * inv + b.y;
    ((float2*)(out + (size_t)node * 128))[lane] = acc;
}

extern "C" void kernel_launch(void* const* d_in, const int* in_sizes, int n_in,
                              void* d_out, int out_size, void* d_ws, size_t ws_size,
                              hipStream_t stream) {
    const float* x    = (const float*)d_in[0];
    const int*   ei   = (const int*)d_in[1];
    const float* W1   = (const float*)d_in[2];
    const float* asr1 = (const float*)d_in[3];
    const float* ads1 = (const float*)d_in[4];
    const float* b1   = (const float*)d_in[5];
    const float* W2   = (const float*)d_in[6];
    const float* asr2 = (const float*)d_in[7];
    const float* ads2 = (const float*)d_in[8];
    const float* b2   = (const float*)d_in[9];
    float* out = (float*)d_out;

    const int N = in_sizes[0] / IN_C;   // 50000
    const int E = in_sizes[1] / 2;      // 500000
    const int NCH = (N + CH - 1) / CH;  // 196

    __hip_bfloat16* hb  = (__hip_bfloat16*)d_ws;      // N*256 bf16 (h1; reused as h2 N*128)
    __hip_bfloat16* xb  = hb + (size_t)N * 256;       // N*256 bf16
    __hip_bfloat16* hel = xb + (size_t)N * 256;       // N*256 bf16
    float* as1 = (float*)(hel + (size_t)N * 256);     // 2N
    float* ad1 = as1 + (size_t)N * 2;                 // 2N
    float* as2 = ad1 + (size_t)N * 2;                 // N
    float* ad2 = as2 + N;                             // N
    int* rowptr = (int*)(ad2 + N);                    // N+1
    int* deg    = rowptr + (N + 1);                   // N
    int* cursor = deg + N;                            // N
    int* csum   = cursor + N;                         // NCH
    int* cbase  = csum + NCH;                         // NCH
    int* adjl   = cbase + NCH;                        // E
    __hip_bfloat16* Wp1 = (__hip_bfloat16*)(adjl + E);   // 65536
    __hip_bfloat16* Wp2 = Wp1 + 65536;                   // 32768

    hipMemsetAsync(deg,    0, (size_t)N * sizeof(int), stream);
    hipMemsetAsync(cursor, 0, (size_t)N * sizeof(int), stream);

    // CSR build
    deg_count<<<(E + 255) / 256, 256, 0, stream>>>(ei, E, deg);
    chunk_reduce<<<NCH, CH, 0, stream>>>(deg, csum, N);
    scan_chunks<<<1, CH, 0, stream>>>(csum, cbase, NCH);
    chunk_scan_write<<<NCH, CH, 0, stream>>>(deg, cbase, rowptr, N);
    csr_fill<<<(E + 255) / 256, 256, 0, stream>>>(ei, E, rowptr, cursor, adjl);

    // weight pack + x convert
    pack_w<256><<<(8 * 16 * 64 + 255) / 256, 256, 0, stream>>>(W1, Wp1);
    pack_w<128><<<(8 * 8 * 64 + 255) / 256, 256, 0, stream>>>(W2, Wp2);
    f2b<<<((N * 64) + 255) / 256, 256, 0, stream>>>((const float4*)x, (ushort4*)xb, N * 64);

    const int gb = ((N + 15) / 16 + 3) / 4;

    // ---- layer 1 ----
    gemm_mfma<16><<<gb, 256, 0, stream>>>(xb, Wp1, hb, N);
    attdots_h2<<<(N + 3) / 4, 256, 0, stream>>>(hb, asr1, ads1, as1, ad1, N);
    aggr_l1<<<(N + 3) / 4, 256, 0, stream>>>(rowptr, adjl, hb, as1, ad1, b1, hel, N);

    // ---- layer 2 ----
    gemm_mfma<8><<<gb, 256, 0, stream>>>(hel, Wp2, hb, N);   // h2 (bf16) into hb
    attdots_h1<<<(N + 3) / 4, 256, 0, stream>>>(hb, asr2, ads2, as2, ad2, N);
    aggr_l2<<<(N + 3) / 4, 256, 0, stream>>>(rowptr, adjl, hb, as2, ad2, b2, out, N);
}